// Round 2
// baseline (119.297 us; speedup 1.0000x reference)
//
#include <hip/hip_runtime.h>
#include <hip/hip_bf16.h>
#include <stdint.h>

// ChebyKAN: y[b,o] = sum_{i,d} T_d(tanh(x[b,i])) * c[i,o,d]
//   == GEMM [16384 x 4096] x [4096 x 512]  (d=1..8; d=0 handled as column-sum)
// A computed on the fly via Chebyshev recurrence; B pre-reordered to bf16
// swizzled tiles in ws (4MB) + colsum f32 (2KB).

#define BM 128
#define BN 128
#define BK 32
#define NSTEPS 128           // 16 i-tiles * 8 d-chunks
#define IN_DIM 512
#define OUT_DIM 512

typedef __attribute__((ext_vector_type(8))) short short8;
typedef __attribute__((ext_vector_type(8))) unsigned short ushort8;
typedef __attribute__((ext_vector_type(4))) float f32x4;

__device__ __forceinline__ unsigned short f2bf(float f) {
  __hip_bfloat16 h = __float2bfloat16(f);
  return __builtin_bit_cast(unsigned short, h);
}

__device__ __forceinline__ float fast_tanh(float v) {
  // tanh(v) = 1 - 2/(exp(2v)+1); exp->inf => 1, exp->0 => -1 (correct limits)
  float e = __expf(v + v);
  return 1.0f - 2.0f * __builtin_amdgcn_rcpf(e + 1.0f);
}

__device__ __forceinline__ void gload_lds16(const void* g, void* l) {
  __builtin_amdgcn_global_load_lds(
      (const __attribute__((address_space(1))) unsigned int*)(uintptr_t)g,
      (__attribute__((address_space(3))) unsigned int*)(uintptr_t)l,
      16, 0, 0);
}

// ---------------------------------------------------------------------------
// Kernel 1: reorder coeffs[i][o][d] (f32) -> ws as bf16 B^T tiles, pre-swizzled.
// Chunk (nb, c) with c = itile*8 + (d-1) is an 8KB image of LDS tile
// [n_local 0..127][k_local 0..31], byte = nl*64 + ((kl*2) ^ ((nl&3)<<4)).
// ---------------------------------------------------------------------------
__global__ __launch_bounds__(256) void cheby_reorder_b(
    const float* __restrict__ coeffs, unsigned char* __restrict__ bws) {
  const int g = blockIdx.x * 256 + threadIdx.x;  // 512*512 threads
  const int i = g & 511;
  const int o = g >> 9;
  const int nb = o >> 7, nl = o & 127;
  const int itile = i >> 5, kl = i & 31;
  const float* cp = coeffs + (size_t)i * 4608 + (size_t)o * 9;
  const int swz = ((kl * 2) ^ ((nl & 3) << 4));
#pragma unroll
  for (int d = 1; d <= 8; ++d) {
    const int c = itile * 8 + (d - 1);
    const size_t byte = ((size_t)(nb * 128 + c) << 13) + (size_t)nl * 64 + swz;
    *(unsigned short*)(bws + byte) = f2bf(cp[d]);
  }
}

// ---------------------------------------------------------------------------
// Kernel 2: colsum[o] = sum_i coeffs[i][o][0]   (T_0 == 1 contribution)
// ---------------------------------------------------------------------------
__global__ __launch_bounds__(64) void cheby_colsum(
    const float* __restrict__ coeffs, float* __restrict__ cs) {
  const int o = blockIdx.x;
  const int l = threadIdx.x;
  float s = 0.0f;
#pragma unroll
  for (int j = 0; j < 8; ++j)
    s += coeffs[(size_t)(l + j * 64) * 4608 + (size_t)o * 9];
#pragma unroll
  for (int off = 32; off > 0; off >>= 1) s += __shfl_down(s, off, 64);
  if (l == 0) cs[o] = s;
}

// ---------------------------------------------------------------------------
// Kernel 3: fused basis-gen + bf16 MFMA GEMM.
// 128x128 tile, BK=32, 4 waves, 16x16x32 mfma, 4x4 frags/wave.
// ---------------------------------------------------------------------------
__global__ __launch_bounds__(256, 2) void cheby_gemm(
    const float* __restrict__ x, const unsigned char* __restrict__ bws,
    const float* __restrict__ colsum, float* __restrict__ out) {
  const int bid = blockIdx.x;
  const int m0 = (bid >> 2) * BM;
  const int nblk = bid & 3;
  const int n0 = nblk * BN;
  const int tid = threadIdx.x;
  const int lane = tid & 63;
  const int wid = tid >> 6;
  const int wm = (wid >> 1) * 64;
  const int wn = (wid & 1) * 64;
  const int l15 = lane & 15;
  const int lhi = lane >> 4;

  __shared__ __align__(16) unsigned char As[BM * BK * 2];  // 8KB swizzled [m][k]
  __shared__ __align__(16) unsigned char Bs[BN * BK * 2];  // 8KB swizzled [n][k]

  // A staging ownership: row = tid>>1, 16 elems (32B) at byte offset (tid&1)*32
  const int srow = tid >> 1;
  const int skb = (tid & 1) * 32;
  unsigned char* Arow = As + srow * 64;
  const int sw0 = (skb) ^ ((srow & 3) << 4);
  const int sw1 = (skb + 16) ^ ((srow & 3) << 4);

  float t2[16], Tm1[16], Tm2[16];
  f32x4 acc[4][4];
#pragma unroll
  for (int a = 0; a < 4; ++a)
#pragma unroll
    for (int b = 0; b < 4; ++b) acc[a][b] = (f32x4){0.f, 0.f, 0.f, 0.f};

  const unsigned char* bchunk0 = bws + ((size_t)(nblk * 128) << 13);

  for (int s = 0; s < NSTEPS; ++s) {
    // ---- issue B tile global->LDS: 8KB = 2 rounds x 4 waves x 64 lanes x 16B
    const unsigned char* gsrc =
        bchunk0 + ((size_t)s << 13) + wid * 1024 + lane * 16;
    gload_lds16(gsrc, Bs + wid * 1024);
    gload_lds16(gsrc + 4096, Bs + wid * 1024 + 4096);

    // ---- A staging: Chebyshev recurrence in registers
    const int dd = s & 7;
    if (dd == 0) {
      const int itile = s >> 3;
      const float* xp =
          x + (size_t)(m0 + srow) * IN_DIM + itile * 32 + (tid & 1) * 16;
#pragma unroll
      for (int j = 0; j < 4; ++j) {
        const float4 v = reinterpret_cast<const float4*>(xp)[j];
        const float a0 = fast_tanh(v.x);
        const float a1 = fast_tanh(v.y);
        const float a2 = fast_tanh(v.z);
        const float a3 = fast_tanh(v.w);
        Tm1[4 * j + 0] = a0; Tm1[4 * j + 1] = a1;
        Tm1[4 * j + 2] = a2; Tm1[4 * j + 3] = a3;
        t2[4 * j + 0] = a0 + a0; t2[4 * j + 1] = a1 + a1;
        t2[4 * j + 2] = a2 + a2; t2[4 * j + 3] = a3 + a3;
        Tm2[4 * j + 0] = 1.0f; Tm2[4 * j + 1] = 1.0f;
        Tm2[4 * j + 2] = 1.0f; Tm2[4 * j + 3] = 1.0f;
      }
    } else {
#pragma unroll
      for (int e = 0; e < 16; ++e) {
        const float T = __builtin_fmaf(t2[e], Tm1[e], -Tm2[e]);
        Tm2[e] = Tm1[e];
        Tm1[e] = T;
      }
    }
    // pack current T_d (== Tm1) to bf16, swizzled ds_write_b128 x2
    ushort8 p0, p1;
#pragma unroll
    for (int j = 0; j < 8; ++j) {
      p0[j] = f2bf(Tm1[j]);
      p1[j] = f2bf(Tm1[j + 8]);
    }
    *(ushort8*)(Arow + sw0) = p0;
    *(ushort8*)(Arow + sw1) = p1;

    __syncthreads();  // drains vmcnt (gload_lds) + lgkmcnt (ds_write)

    short8 af[4], bfr[4];
#pragma unroll
    for (int fm = 0; fm < 4; ++fm) {
      const int row = wm + fm * 16 + l15;
      af[fm] = *(const short8*)(As + row * 64 + ((lhi * 16) ^ ((row & 3) << 4)));
    }
#pragma unroll
    for (int fn = 0; fn < 4; ++fn) {
      const int row = wn + fn * 16 + l15;
      bfr[fn] = *(const short8*)(Bs + row * 64 + ((lhi * 16) ^ ((row & 3) << 4)));
    }
#pragma unroll
    for (int fm = 0; fm < 4; ++fm)
#pragma unroll
      for (int fn = 0; fn < 4; ++fn)
        acc[fm][fn] = __builtin_amdgcn_mfma_f32_16x16x32_bf16(
            af[fm], bfr[fn], acc[fm][fn], 0, 0, 0);

    __syncthreads();  // protect As/Bs reuse next iter
  }

  // ---- epilogue: add d=0 colsum, store f32
  float csv[4];
#pragma unroll
  for (int fn = 0; fn < 4; ++fn) csv[fn] = colsum[n0 + wn + fn * 16 + l15];
#pragma unroll
  for (int fm = 0; fm < 4; ++fm) {
    const int r0 = m0 + wm + fm * 16 + lhi * 4;
#pragma unroll
    for (int fn = 0; fn < 4; ++fn) {
      const int col = n0 + wn + fn * 16 + l15;
#pragma unroll
      for (int r = 0; r < 4; ++r)
        out[(size_t)(r0 + r) * OUT_DIM + col] = acc[fm][fn][r] + csv[fn];
    }
  }
}

extern "C" void kernel_launch(void* const* d_in, const int* in_sizes, int n_in,
                              void* d_out, int out_size, void* d_ws,
                              size_t ws_size, hipStream_t stream) {
  const float* x = (const float*)d_in[0];           // [16384, 512] f32
  const float* coeffs = (const float*)d_in[1];      // [512, 512, 9] f32
  float* out = (float*)d_out;                       // [16384, 512] f32
  unsigned char* bws = (unsigned char*)d_ws;        // 4MB bf16 B tiles
  float* cs = (float*)((unsigned char*)d_ws + ((size_t)4 << 20));  // +2KB

  hipLaunchKernelGGL(cheby_reorder_b, dim3(1024), dim3(256), 0, stream, coeffs,
                     bws);
  hipLaunchKernelGGL(cheby_colsum, dim3(512), dim3(64), 0, stream, coeffs, cs);
  hipLaunchKernelGGL(cheby_gemm, dim3(512), dim3(256), 0, stream, x, bws, cs,
                     out);
}

// Round 5
// 110.400 us; speedup vs baseline: 1.0806x; 1.0806x over previous
//
#include <hip/hip_runtime.h>
#include <hip/hip_bf16.h>
#include <stdint.h>

// ChebyKAN: y[b,o] = sum_{i,d} T_d(tanh(x[b,i])) * c[i,o,d]
//   == GEMM [16384 x 4096] x [4096 x 512]  (d=1..8; d=0 handled as column-sum)
// A computed on the fly via Chebyshev recurrence; B pre-reordered to bf16
// swizzled tiles in ws (4MB) + colsum f32 (2KB).
//
// R2 changes: (a) swizzle fixed to ((row>>1)&3)<<4 — old (row&3)<<4 had
// period 4 rows vs 2-row bank period => 4-way read conflict (1.26e7 cycles);
// new form covers all 8 16B slots per 8 rows => 2-way (free).
// (b) 512 threads / 8 waves per block (wave tile 64x32) => 16 waves/CU.

#define BM 128
#define BN 128
#define BK 32
#define NSTEPS 128           // 16 i-tiles * 8 d-chunks
#define IN_DIM 512
#define OUT_DIM 512

typedef __attribute__((ext_vector_type(8))) short short8;
typedef __attribute__((ext_vector_type(8))) unsigned short ushort8;
typedef __attribute__((ext_vector_type(4))) float f32x4;

__device__ __forceinline__ unsigned short f2bf(float f) {
  __hip_bfloat16 h = __float2bfloat16(f);
  return __builtin_bit_cast(unsigned short, h);
}

__device__ __forceinline__ float fast_tanh(float v) {
  // tanh(v) = 1 - 2/(exp(2v)+1); exp->inf => 1, exp->0 => -1 (correct limits)
  float e = __expf(v + v);
  return 1.0f - 2.0f * __builtin_amdgcn_rcpf(e + 1.0f);
}

__device__ __forceinline__ void gload_lds16(const void* g, void* l) {
  __builtin_amdgcn_global_load_lds(
      (const __attribute__((address_space(1))) unsigned int*)(uintptr_t)g,
      (__attribute__((address_space(3))) unsigned int*)(uintptr_t)l,
      16, 0, 0);
}

// ---------------------------------------------------------------------------
// Kernel 1: reorder coeffs[i][o][d] (f32) -> ws as bf16 B^T tiles, pre-swizzled.
// Chunk (nb, c) with c = itile*8 + (d-1) is an 8KB image of LDS tile
// [n_local 0..127][k_local 0..31], byte = nl*64 + ((kl*2) ^ (((nl>>1)&3)<<4)).
// ---------------------------------------------------------------------------
__global__ __launch_bounds__(256) void cheby_reorder_b(
    const float* __restrict__ coeffs, unsigned char* __restrict__ bws) {
  const int g = blockIdx.x * 256 + threadIdx.x;  // 512*512 threads
  const int i = g & 511;
  const int o = g >> 9;
  const int nb = o >> 7, nl = o & 127;
  const int itile = i >> 5, kl = i & 31;
  const float* cp = coeffs + (size_t)i * 4608 + (size_t)o * 9;
  const int swz = ((kl * 2) ^ (((nl >> 1) & 3) << 4));
#pragma unroll
  for (int d = 1; d <= 8; ++d) {
    const int c = itile * 8 + (d - 1);
    const size_t byte = ((size_t)(nb * 128 + c) << 13) + (size_t)nl * 64 + swz;
    *(unsigned short*)(bws + byte) = f2bf(cp[d]);
  }
}

// ---------------------------------------------------------------------------
// Kernel 2: colsum[o] = sum_i coeffs[i][o][0]   (T_0 == 1 contribution)
// ---------------------------------------------------------------------------
__global__ __launch_bounds__(64) void cheby_colsum(
    const float* __restrict__ coeffs, float* __restrict__ cs) {
  const int o = blockIdx.x;
  const int l = threadIdx.x;
  float s = 0.0f;
#pragma unroll
  for (int j = 0; j < 8; ++j)
    s += coeffs[(size_t)(l + j * 64) * 4608 + (size_t)o * 9];
#pragma unroll
  for (int off = 32; off > 0; off >>= 1) s += __shfl_down(s, off, 64);
  if (l == 0) cs[o] = s;
}

// ---------------------------------------------------------------------------
// Kernel 3: fused basis-gen + bf16 MFMA GEMM.
// 128x128 tile, BK=32, 8 waves (wave tile 64x32), 16x16x32 mfma, 4x2 frags.
// ---------------------------------------------------------------------------
__global__ __launch_bounds__(512, 4) void cheby_gemm(
    const float* __restrict__ x, const unsigned char* __restrict__ bws,
    const float* __restrict__ colsum, float* __restrict__ out) {
  const int bid = blockIdx.x;
  const int m0 = (bid >> 2) * BM;
  const int nblk = bid & 3;
  const int n0 = nblk * BN;
  const int tid = threadIdx.x;
  const int lane = tid & 63;
  const int wid = tid >> 6;          // 0..7
  const int wm = (wid >> 2) * 64;    // 2 wave-rows of 64
  const int wn = (wid & 3) * 32;     // 4 wave-cols of 32
  const int l15 = lane & 15;
  const int lhi = lane >> 4;

  __shared__ __align__(16) unsigned char As[BM * BK * 2];  // 8KB swizzled [m][k]
  __shared__ __align__(16) unsigned char Bs[BN * BK * 2];  // 8KB swizzled [n][k]

  // A staging ownership: row = tid>>2, 8 elems (16B) at elem offset (tid&3)*8
  const int srow = tid >> 2;
  const int skb = (tid & 3) * 16;                    // byte offset in row
  unsigned char* Arow = As + srow * 64;
  const int sw = skb ^ (((srow >> 1) & 3) << 4);

  float t2[8], Tm1[8], Tm2[8];
  f32x4 acc[4][2];
#pragma unroll
  for (int a = 0; a < 4; ++a)
#pragma unroll
    for (int b = 0; b < 2; ++b) acc[a][b] = (f32x4){0.f, 0.f, 0.f, 0.f};

  const unsigned char* bchunk0 = bws + ((size_t)(nblk * 128) << 13);

  for (int s = 0; s < NSTEPS; ++s) {
    // ---- issue B tile global->LDS: 8KB = 8 waves x 64 lanes x 16B
    gload_lds16(bchunk0 + ((size_t)s << 13) + tid * 16, Bs + wid * 1024);

    // ---- A staging: Chebyshev recurrence in registers (8 elems/thread)
    const int dd = s & 7;
    if (dd == 0) {
      const int itile = s >> 3;
      const float* xp =
          x + (size_t)(m0 + srow) * IN_DIM + itile * 32 + (tid & 3) * 8;
#pragma unroll
      for (int j = 0; j < 2; ++j) {
        const float4 v = reinterpret_cast<const float4*>(xp)[j];
        const float a0 = fast_tanh(v.x);
        const float a1 = fast_tanh(v.y);
        const float a2 = fast_tanh(v.z);
        const float a3 = fast_tanh(v.w);
        Tm1[4 * j + 0] = a0; Tm1[4 * j + 1] = a1;
        Tm1[4 * j + 2] = a2; Tm1[4 * j + 3] = a3;
        t2[4 * j + 0] = a0 + a0; t2[4 * j + 1] = a1 + a1;
        t2[4 * j + 2] = a2 + a2; t2[4 * j + 3] = a3 + a3;
        Tm2[4 * j + 0] = 1.0f; Tm2[4 * j + 1] = 1.0f;
        Tm2[4 * j + 2] = 1.0f; Tm2[4 * j + 3] = 1.0f;
      }
    } else {
#pragma unroll
      for (int e = 0; e < 8; ++e) {
        const float T = __builtin_fmaf(t2[e], Tm1[e], -Tm2[e]);
        Tm2[e] = Tm1[e];
        Tm1[e] = T;
      }
    }
    // pack current T_d (== Tm1) to bf16, one swizzled ds_write_b128
    ushort8 p0;
#pragma unroll
    for (int j = 0; j < 8; ++j) p0[j] = f2bf(Tm1[j]);
    *(ushort8*)(Arow + sw) = p0;

    __syncthreads();  // drains vmcnt (gload_lds) + lgkmcnt (ds_write)

    short8 af[4], bfr[2];
#pragma unroll
    for (int fm = 0; fm < 4; ++fm) {
      const int row = wm + fm * 16 + l15;
      af[fm] = *(const short8*)(As + row * 64 +
                                ((lhi * 16) ^ (((row >> 1) & 3) << 4)));
    }
#pragma unroll
    for (int fn = 0; fn < 2; ++fn) {
      const int row = wn + fn * 16 + l15;
      bfr[fn] = *(const short8*)(Bs + row * 64 +
                                 ((lhi * 16) ^ (((row >> 1) & 3) << 4)));
    }
#pragma unroll
    for (int fm = 0; fm < 4; ++fm)
#pragma unroll
      for (int fn = 0; fn < 2; ++fn)
        acc[fm][fn] = __builtin_amdgcn_mfma_f32_16x16x32_bf16(
            af[fm], bfr[fn], acc[fm][fn], 0, 0, 0);

    __syncthreads();  // protect As/Bs reuse next iter
  }

  // ---- epilogue: add d=0 colsum, store f32
  float csv[2];
#pragma unroll
  for (int fn = 0; fn < 2; ++fn) csv[fn] = colsum[n0 + wn + fn * 16 + l15];
#pragma unroll
  for (int fm = 0; fm < 4; ++fm) {
    const int r0 = m0 + wm + fm * 16 + lhi * 4;
#pragma unroll
    for (int fn = 0; fn < 2; ++fn) {
      const int col = n0 + wn + fn * 16 + l15;
#pragma unroll
      for (int r = 0; r < 4; ++r)
        out[(size_t)(r0 + r) * OUT_DIM + col] = acc[fm][fn][r] + csv[fn];
    }
  }
}

extern "C" void kernel_launch(void* const* d_in, const int* in_sizes, int n_in,
                              void* d_out, int out_size, void* d_ws,
                              size_t ws_size, hipStream_t stream) {
  const float* x = (const float*)d_in[0];           // [16384, 512] f32
  const float* coeffs = (const float*)d_in[1];      // [512, 512, 9] f32
  float* out = (float*)d_out;                       // [16384, 512] f32
  unsigned char* bws = (unsigned char*)d_ws;        // 4MB bf16 B tiles
  float* cs = (float*)((unsigned char*)d_ws + ((size_t)4 << 20));  // +2KB

  hipLaunchKernelGGL(cheby_reorder_b, dim3(1024), dim3(256), 0, stream, coeffs,
                     bws);
  hipLaunchKernelGGL(cheby_colsum, dim3(512), dim3(64), 0, stream, coeffs, cs);
  hipLaunchKernelGGL(cheby_gemm, dim3(512), dim3(512), 0, stream, x, bws, cs,
                     out);
}

// Round 6
// 97.527 us; speedup vs baseline: 1.2232x; 1.1320x over previous
//
#include <hip/hip_runtime.h>
#include <hip/hip_bf16.h>
#include <stdint.h>

// ChebyKAN: y[b,o] = sum_{i,d} T_d(tanh(x[b,i])) * c[i,o,d]
//   == GEMM [16384 x 4096] x [4096 x 512]  (d=1..8; d=0 via column-sum)
// A generated on the fly (Chebyshev recurrence, 2 degrees per K-step);
// B pre-reordered to bf16 swizzled tiles in ws (4MB) + colsum f32 (2KB).
//
// R6: wave tile 64x64 (4 waves/block, 256 thr), BK=64 (32 i x 2 d) ->
// 16 ds_read_b128 per 32 MFMA (was 6 per 8), 64 barrier-pairs (was 128).
// Swizzle: full-offset XOR with ((row&7)<<4), rows are 128 B.

#define BM 128
#define BN 128
#define BK 64              // 32 i-elems x 2 degrees
#define NSTEPS 64          // 16 i-tiles * 4 degree-pairs
#define IN_DIM 512
#define OUT_DIM 512

typedef __attribute__((ext_vector_type(8))) short short8;
typedef __attribute__((ext_vector_type(8))) unsigned short ushort8;
typedef __attribute__((ext_vector_type(4))) float f32x4;

__device__ __forceinline__ unsigned short f2bf(float f) {
  __hip_bfloat16 h = __float2bfloat16(f);
  return __builtin_bit_cast(unsigned short, h);
}

__device__ __forceinline__ float fast_tanh(float v) {
  float e = __expf(v + v);
  return 1.0f - 2.0f * __builtin_amdgcn_rcpf(e + 1.0f);
}

__device__ __forceinline__ void gload_lds16(const void* g, void* l) {
  __builtin_amdgcn_global_load_lds(
      (const __attribute__((address_space(1))) unsigned int*)(uintptr_t)g,
      (__attribute__((address_space(3))) unsigned int*)(uintptr_t)l,
      16, 0, 0);
}

// ---------------------------------------------------------------------------
// Kernel 1: coeffs[i][o][d] (f32) -> ws: bf16 B^T chunks, pre-swizzled.
// Chunk (nb, c) with c = itile*4 + p is a 16KB image of LDS tile
// [nl 0..127][128 B]: elem (il, dl) at byte nl*128 + ((dl*64+il*2)^((nl&7)<<4)),
// holding coeff d = 1 + 2p + dl.
// ---------------------------------------------------------------------------
__global__ __launch_bounds__(256) void cheby_reorder_b(
    const float* __restrict__ coeffs, unsigned char* __restrict__ bws) {
  const int g = blockIdx.x * 256 + threadIdx.x;  // 512*512 threads
  const int i = g & 511;
  const int o = g >> 9;
  const int nb = o >> 7, nl = o & 127;
  const int itile = i >> 5, il = i & 31;
  const float* cp = coeffs + (size_t)i * 4608 + (size_t)o * 9;
  const int swz = (nl & 7) << 4;
#pragma unroll
  for (int p = 0; p < 4; ++p) {
    const size_t base =
        ((size_t)(nb * 64 + itile * 4 + p) << 14) + (size_t)nl * 128;
    *(unsigned short*)(bws + base + ((il * 2) ^ swz)) = f2bf(cp[1 + 2 * p]);
    *(unsigned short*)(bws + base + ((64 + il * 2) ^ swz)) =
        f2bf(cp[2 + 2 * p]);
  }
}

// ---------------------------------------------------------------------------
// Kernel 2: colsum[o] = sum_i coeffs[i][o][0]   (T_0 == 1 contribution)
// ---------------------------------------------------------------------------
__global__ __launch_bounds__(64) void cheby_colsum(
    const float* __restrict__ coeffs, float* __restrict__ cs) {
  const int o = blockIdx.x;
  const int l = threadIdx.x;
  float s = 0.0f;
#pragma unroll
  for (int j = 0; j < 8; ++j)
    s += coeffs[(size_t)(l + j * 64) * 4608 + (size_t)o * 9];
#pragma unroll
  for (int off = 32; off > 0; off >>= 1) s += __shfl_down(s, off, 64);
  if (l == 0) cs[o] = s;
}

// ---------------------------------------------------------------------------
// Kernel 3: fused basis-gen + bf16 MFMA GEMM.
// 128x128 tile, BK=64, 4 waves (wave tile 64x64), 16x16x32 mfma, 4x4 frags.
// ---------------------------------------------------------------------------
__global__ __launch_bounds__(256, 3) void cheby_gemm(
    const float* __restrict__ x, const unsigned char* __restrict__ bws,
    const float* __restrict__ colsum, float* __restrict__ out) {
  const int bid = blockIdx.x;
  const int m0 = (bid >> 2) * BM;
  const int nblk = bid & 3;
  const int n0 = nblk * BN;
  const int tid = threadIdx.x;
  const int lane = tid & 63;
  const int wid = tid >> 6;          // 0..3
  const int wm = (wid >> 1) * 64;
  const int wn = (wid & 1) * 64;
  const int l15 = lane & 15;
  const int lhi = lane >> 4;

  __shared__ __align__(16) unsigned char As[BM * 128];  // 16KB swizzled [m][k]
  __shared__ __align__(16) unsigned char Bs[BN * 128];  // 16KB swizzled [n][k]

  // A staging: thread owns (srow = tid>>1, 16 i-elems at il = (tid&1)*16)
  const int srow = tid >> 1;
  const int ihalf = tid & 1;
  unsigned char* Arow = As + srow * 128;
  const int aswz = (srow & 7) << 4;
  const int wbase = ihalf * 32;      // byte offset of this thread's 16 elems

  float t2[16], Tm1[16], Tm2[16];
  f32x4 acc[4][4];
#pragma unroll
  for (int a = 0; a < 4; ++a)
#pragma unroll
    for (int b = 0; b < 4; ++b) acc[a][b] = (f32x4){0.f, 0.f, 0.f, 0.f};

  const unsigned char* bchunk0 = bws + ((size_t)(nblk * 64) << 14);

  for (int s = 0; s < NSTEPS; ++s) {
    // ---- B tile global->LDS: 16KB = 4 waves x 4 x (64 lanes x 16B)
    const unsigned char* gsrc =
        bchunk0 + ((size_t)s << 14) + wid * 4096 + lane * 16;
    unsigned char* ldst = Bs + wid * 4096;
    gload_lds16(gsrc, ldst);
    gload_lds16(gsrc + 1024, ldst + 1024);
    gload_lds16(gsrc + 2048, ldst + 2048);
    gload_lds16(gsrc + 3072, ldst + 3072);

    // ---- A staging: advance recurrence 2 degrees; Tm2 = T_{d0}, Tm1 = T_{d1}
    const int p = s & 3;
    if (p == 0) {
      const int itile = s >> 2;
      const float* xp =
          x + (size_t)(m0 + srow) * IN_DIM + itile * 32 + ihalf * 16;
#pragma unroll
      for (int j = 0; j < 4; ++j) {
        const float4 v = reinterpret_cast<const float4*>(xp)[j];
        const float a0 = fast_tanh(v.x);
        const float a1 = fast_tanh(v.y);
        const float a2 = fast_tanh(v.z);
        const float a3 = fast_tanh(v.w);
        Tm2[4 * j + 0] = a0; Tm2[4 * j + 1] = a1;
        Tm2[4 * j + 2] = a2; Tm2[4 * j + 3] = a3;
        t2[4 * j + 0] = a0 + a0; t2[4 * j + 1] = a1 + a1;
        t2[4 * j + 2] = a2 + a2; t2[4 * j + 3] = a3 + a3;
        Tm1[4 * j + 0] = __builtin_fmaf(a0 + a0, a0, -1.0f);
        Tm1[4 * j + 1] = __builtin_fmaf(a1 + a1, a1, -1.0f);
        Tm1[4 * j + 2] = __builtin_fmaf(a2 + a2, a2, -1.0f);
        Tm1[4 * j + 3] = __builtin_fmaf(a3 + a3, a3, -1.0f);
      }
    } else {
#pragma unroll
      for (int e = 0; e < 16; ++e) {
        const float Ta = __builtin_fmaf(t2[e], Tm1[e], -Tm2[e]);
        const float Tb = __builtin_fmaf(t2[e], Ta, -Tm1[e]);
        Tm2[e] = Ta;
        Tm1[e] = Tb;
      }
    }
    // pack (T_{d0}, T_{d1}) to bf16; 4 swizzled ds_write_b128
    ushort8 pa0, pa1, pb0, pb1;
#pragma unroll
    for (int j = 0; j < 8; ++j) {
      pa0[j] = f2bf(Tm2[j]);
      pa1[j] = f2bf(Tm2[j + 8]);
      pb0[j] = f2bf(Tm1[j]);
      pb1[j] = f2bf(Tm1[j + 8]);
    }
    *(ushort8*)(Arow + ((wbase) ^ aswz)) = pa0;
    *(ushort8*)(Arow + ((wbase + 16) ^ aswz)) = pa1;
    *(ushort8*)(Arow + ((64 + wbase) ^ aswz)) = pb0;
    *(ushort8*)(Arow + ((64 + wbase + 16) ^ aswz)) = pb1;

    __syncthreads();  // drains vmcnt (gload_lds) + lgkmcnt (ds_write)

#pragma unroll
    for (int ks = 0; ks < 2; ++ks) {
      short8 af[4];
#pragma unroll
      for (int fm = 0; fm < 4; ++fm) {
        const int row = wm + fm * 16 + l15;
        af[fm] = *(const short8*)(
            As + row * 128 + ((ks * 64 + lhi * 16) ^ ((row & 7) << 4)));
      }
#pragma unroll
      for (int fn = 0; fn < 4; ++fn) {
        const int row = wn + fn * 16 + l15;
        const short8 bf = *(const short8*)(
            Bs + row * 128 + ((ks * 64 + lhi * 16) ^ ((row & 7) << 4)));
#pragma unroll
        for (int fm = 0; fm < 4; ++fm)
          acc[fm][fn] = __builtin_amdgcn_mfma_f32_16x16x32_bf16(
              af[fm], bf, acc[fm][fn], 0, 0, 0);
      }
    }
    __syncthreads();  // protect As/Bs reuse next iter
  }

  // ---- epilogue: add d=0 colsum, store f32
  float csv[4];
#pragma unroll
  for (int fn = 0; fn < 4; ++fn) csv[fn] = colsum[n0 + wn + fn * 16 + l15];
#pragma unroll
  for (int fm = 0; fm < 4; ++fm) {
    const int r0 = m0 + wm + fm * 16 + lhi * 4;
#pragma unroll
    for (int fn = 0; fn < 4; ++fn) {
      const int col = n0 + wn + fn * 16 + l15;
#pragma unroll
      for (int r = 0; r < 4; ++r)
        out[(size_t)(r0 + r) * OUT_DIM + col] = acc[fm][fn][r] + csv[fn];
    }
  }
}

extern "C" void kernel_launch(void* const* d_in, const int* in_sizes, int n_in,
                              void* d_out, int out_size, void* d_ws,
                              size_t ws_size, hipStream_t stream) {
  const float* x = (const float*)d_in[0];           // [16384, 512] f32
  const float* coeffs = (const float*)d_in[1];      // [512, 512, 9] f32
  float* out = (float*)d_out;                       // [16384, 512] f32
  unsigned char* bws = (unsigned char*)d_ws;        // 4MB bf16 B tiles
  float* cs = (float*)((unsigned char*)d_ws + ((size_t)4 << 20));  // +2KB

  hipLaunchKernelGGL(cheby_reorder_b, dim3(1024), dim3(256), 0, stream, coeffs,
                     bws);
  hipLaunchKernelGGL(cheby_colsum, dim3(512), dim3(64), 0, stream, coeffs, cs);
  hipLaunchKernelGGL(cheby_gemm, dim3(512), dim3(256), 0, stream, x, bws, cs,
                     out);
}